// Round 11
// baseline (1120.377 us; speedup 1.0000x reference)
//
#include <hip/hip_runtime.h>
#include <math.h>

#define NN   65536
#define EE   32768
#define HH   256
#define KK   24
#define DDIM 1280
#define OUTD 512
#define NT   (DDIM / 64)   // 20 K-iterations of 64
#define GCAP 1024
#define MAXCHUNK 4

typedef _Float16 half8 __attribute__((ext_vector_type(8)));
typedef _Float16 half4 __attribute__((ext_vector_type(4)));
typedef float    f32x4 __attribute__((ext_vector_type(4)));

__device__ __forceinline__ float elu1(float x) { return x > 0.f ? x : expm1f(x); }

__device__ __forceinline__ void gl16(const void* g, void* l) {
    __builtin_amdgcn_global_load_lds(
        (const __attribute__((address_space(1))) void*)g,
        (__attribute__((address_space(3))) void*)l, 16, 0, 0);
}

// ---------------------------------------------------------------------------
// Fragment-major, kt-major layout contract (A16 / W16 / both GEMM operands):
// element (row, k) lives in subtile (kt32 = k/32, ms = row/16), chunk
// c = (row%16) + 16*((k%32)/8), byte 2*(k%8). Subtile = 64 chunks x 16 B.
// Global subtile index: kt32 * SUBS_PER_KT + ms (SUBS_PER_KT = nms for A
// rows, nspk for W cols). Per-kt32 slices contiguous -> staging is linear.
// ---------------------------------------------------------------------------
__global__ __launch_bounds__(256) void prep_kernel(
    const float* __restrict__ Wd, const float* __restrict__ Wo,
    _Float16* __restrict__ W16d, _Float16* __restrict__ W16o,
    int* __restrict__ cnt)
{
    const int b = blockIdx.x;
    const int w = threadIdx.x >> 6;
    const int lane = threadIdx.x & 63;
    if (b < 2400) {                       // 3 square layers, 3200 subtiles each
        const int l = b / 800;
        const int s = (b % 800) * 4 + w;  // s = kt32*80 + ns
        const int ns = s % 80, kt = s / 80;
        const int n = ns * 16 + (lane & 15);
        const int kbase = kt * 32 + 8 * (lane >> 4);
        const float* W = Wd + (size_t)l * DDIM * DDIM;
        half8 v;
        #pragma unroll
        for (int j = 0; j < 8; ++j) v[j] = (_Float16)W[(size_t)(kbase + j) * DDIM + n];
        ((half8*)(W16d + (size_t)l * DDIM * DDIM))[(size_t)s * 64 + lane] = v;
    } else if (b < 2720) {                // output layer, 1280 subtiles
        const int s = (b - 2400) * 4 + w; // s = kt32*32 + ns
        const int ns = s % 32, kt = s / 32;
        const int n = ns * 16 + (lane & 15);
        const int kbase = kt * 32 + 8 * (lane >> 4);
        half8 v;
        #pragma unroll
        for (int j = 0; j < 8; ++j) v[j] = (_Float16)Wo[(size_t)(kbase + j) * OUTD + n];
        ((half8*)W16o)[(size_t)s * 64 + lane] = v;
    } else {
        if (threadIdx.x < 64 * MAXCHUNK) cnt[threadIdx.x] = 0;
    }
}

__global__ __launch_bounds__(256) void scatter_kernel(
    const int* __restrict__ src_idx, const int* __restrict__ batch_vec,
    int* __restrict__ perm, int* __restrict__ cnt, int nE)
{
    __shared__ int lc[64];
    __shared__ int lbase[64];
    const int tid = threadIdx.x;
    if (tid < 64) lc[tid] = 0;
    __syncthreads();
    const int e = blockIdx.x * 256 + tid;
    int g = -1, li = 0;
    if (e < nE) {
        g = batch_vec[src_idx[e]];
        li = atomicAdd(&lc[g], 1);
    }
    __syncthreads();
    if (tid < 64 && lc[tid] > 0) lbase[tid] = atomicAdd(&cnt[tid], lc[tid]);
    __syncthreads();
    if (e >= nE) return;
    const int idx = lbase[g] + li;
    if (idx < GCAP) perm[g * GCAP + idx] = e;
}

// ---------------------------------------------------------------------------
// Feature assembly -> row-major fp32 (residual) + kt-major fragment fp16.
// ---------------------------------------------------------------------------
__global__ __launch_bounds__(256) void feats4_kernel(
    const float* __restrict__ X, const int* __restrict__ perm,
    const int* __restrict__ cnt,
    const int* __restrict__ src_idx, const int* __restrict__ dst_idx,
    const int* __restrict__ ptrv,
    const int* __restrict__ sl, const int* __restrict__ sr,
    const float* __restrict__ elem, const float* __restrict__ emb,
    const float* __restrict__ stat,
    float* __restrict__ F32, _Float16* __restrict__ F16, int nms)
{
    const int b  = blockIdx.x;
    const int x  = b & 7;
    const int j  = b >> 3;
    const int g  = x + 8 * (j >> 8);
    const int jj = j & 255;
    const int slot = jj * 4 + (threadIdx.x >> 6);
    const int ng = min(cnt[g], GCAP);
    if (slot >= ng) return;
    const int e = perm[g * GCAP + slot];

    const int lane = threadIdx.x & 63;
    const int src  = src_idx[e];
    const int dst  = dst_idx[e];
    const int off  = ptrv[g];

    const float4* X4 = (const float4*)X;
    float4* f4 = (float4*)(F32 + (size_t)e * DDIM);

    // fragment-major half4 dest for (seg, lane): kt = seg*8 + lane/8,
    // chunk = (e%16) + 16*((lane%8)/2), element offset (lane&1)*4.
    const int klane = lane >> 3;
    const size_t cbase = (size_t)((e & 15) + (((lane & 7) >> 1) << 4)) * 8 + (lane & 1) * 4;
    const size_t msub  = (size_t)(e >> 4);
#define ST(seg, v)                                                            \
    {                                                                         \
        f4[(seg) * 64 + lane] = (v);                                          \
        half4 h_;                                                             \
        h_[0] = (_Float16)(v).x; h_[1] = (_Float16)(v).y;                     \
        h_[2] = (_Float16)(v).z; h_[3] = (_Float16)(v).w;                     \
        const size_t kt_ = (size_t)((seg) * 8 + klane);                       \
        *(half4*)(F16 + (kt_ * nms + msub) * 512 + cbase) = h_;               \
    }

    ST(0, X4[(size_t)src * 64 + lane]);
    ST(1, X4[(size_t)dst * 64 + lane]);

    float4 sL = make_float4(0.f, 0.f, 0.f, 0.f);
    float4 sR = make_float4(0.f, 0.f, 0.f, 0.f);
    int cL = 0, cR = 0;
    #pragma unroll
    for (int k = 0; k < KK; ++k) {
        const int il  = sl[e * KK + k] + off;
        const int ir  = sr[e * KK + k] + off;
        const int okL = il >= 0;
        const int okR = ir >= 0;
        const float wL = okL ? 1.f : 0.f;
        const float wR = okR ? 1.f : 0.f;
        const float4 vl = X4[(size_t)(okL ? il : 0) * 64 + lane];
        const float4 vr = X4[(size_t)(okR ? ir : 0) * 64 + lane];
        sL.x += vl.x * wL; sL.y += vl.y * wL; sL.z += vl.z * wL; sL.w += vl.w * wL;
        sR.x += vr.x * wR; sR.y += vr.y * wR; sR.z += vr.z * wR; sR.w += vr.w * wR;
        cL += okL; cR += okR;
    }
    const float rL = cL > 0 ? 1.f / (float)cL : 0.f;
    const float rR = cR > 0 ? 1.f / (float)cR : 0.f;
    ST(2, make_float4(sL.x * rL, sL.y * rL, sL.z * rL, sL.w * rL));
    ST(3, make_float4(sR.x * rR, sR.y * rR, sR.z * rR, sR.w * rR));

    float4 tail;
    if (lane < 6)       tail = ((const float4*)(elem + (size_t)e * 24))[lane];
    else if (lane < 56) tail = ((const float4*)(emb  + (size_t)e * 200))[lane - 6];
    else                tail = ((const float4*)(stat + (size_t)e * 32))[lane - 56];
    ST(4, tail);
#undef ST
}

// ---------------------------------------------------------------------------
// 8-wave MFMA GEMM: BM=256, BN=64*NS (NS=5 -> 320, NS=4 -> 256), BK=64,
// wave tile 128 x (16*NS), double-buffered LDS + counted vmcnt (never 0 in
// main loop), 4 MFMA sub-phases per iteration, setprio around MFMA.
// ---------------------------------------------------------------------------
template<int NS, bool RESID, bool OUT32, bool H16>
__global__ __launch_bounds__(512, 2) void mfma_gemm5(
    const _Float16* __restrict__ A16, const float* __restrict__ R32,
    const _Float16* __restrict__ W16, const float* __restrict__ bias,
    float* __restrict__ C32, _Float16* __restrict__ C16,
    int N, int nspk, int nms)
{
    __shared__ __align__(16) char sA[2][32768];
    __shared__ __align__(16) char sB[2][NS * 8192];

    const int t    = threadIdx.x;
    const int wid  = t >> 6;
    const int lane = t & 63;
    const int wm = wid >> 2, wn = wid & 3;

    const int ntn = N / (NS * 64);
    int wg = blockIdx.x;
    if ((gridDim.x & 7) == 0)
        wg = (wg & 7) * (gridDim.x >> 3) + (wg >> 3);   // chunked XCD swizzle
    const int m_t = wg / ntn, n_t = wg % ntn;
    const int m0s = m_t * 16;
    const int n0s = n_t * 4 * NS;

    // staging assignment: per stage, wave does 4 A-calls + NS B-calls of 1 KB
    int gAsub[4], lA[4], gBsub[NS], lB[NS];
    #pragma unroll
    for (int i = 0; i < 4; ++i) {
        const int o = wid + i * 8;
        lA[i] = o;
        gAsub[i] = ((o >> 4) ? nms : 0) + m0s + (o & 15);
    }
    #pragma unroll
    for (int i = 0; i < NS; ++i) {
        const int o = wid + i * 8;
        lB[i] = o;
        const int kth = o / (4 * NS);
        gBsub[i] = (kth ? nspk : 0) + n0s + (o - kth * 4 * NS);
    }

#define STAGE(d, ktv)                                                          \
    {                                                                          \
        const size_t kbA = (size_t)((ktv) * 2) * nms;                          \
        const size_t kbB = (size_t)((ktv) * 2) * nspk;                         \
        _Pragma("unroll")                                                      \
        for (int i = 0; i < 4; ++i)                                            \
            gl16((const char*)A16 + ((kbA + gAsub[i]) << 10) + lane * 16,      \
                 sA[d] + lA[i] * 1024);                                        \
        _Pragma("unroll")                                                      \
        for (int i = 0; i < NS; ++i)                                           \
            gl16((const char*)W16 + ((kbB + gBsub[i]) << 10) + lane * 16,      \
                 sB[d] + lB[i] * 1024);                                        \
    }

    f32x4 acc[8][NS];
    #pragma unroll
    for (int q = 0; q < 8; ++q)
        #pragma unroll
        for (int p = 0; p < NS; ++p) acc[q][p] = (f32x4){0.f, 0.f, 0.f, 0.f};

    STAGE(0, 0);
    STAGE(1, 1);

    int cur = 0;
    for (int kt = 0; kt < NT; ++kt) {
        if (kt + 1 < NT) {
            if constexpr (NS == 5) asm volatile("s_waitcnt vmcnt(9)" ::: "memory");
            else                   asm volatile("s_waitcnt vmcnt(8)" ::: "memory");
        } else {
            asm volatile("s_waitcnt vmcnt(0)" ::: "memory");
        }
        __builtin_amdgcn_sched_barrier(0);
        __builtin_amdgcn_s_barrier();          // stage kt visible to all waves
        __builtin_amdgcn_sched_barrier(0);

        const half8* pA = (const half8*)sA[cur];
        const half8* pB = (const half8*)sB[cur];
        half8 bf[2][NS], af[4];

        // P1: all B frags + A q0..3 kth0
        #pragma unroll
        for (int kh = 0; kh < 2; ++kh)
            #pragma unroll
            for (int p = 0; p < NS; ++p)
                bf[kh][p] = pB[(kh * 4 * NS + wn * NS + p) * 64 + lane];
        #pragma unroll
        for (int q = 0; q < 4; ++q) af[q] = pA[(wm * 8 + q) * 64 + lane];
        asm volatile("s_waitcnt lgkmcnt(0)" ::: "memory");
        __builtin_amdgcn_sched_barrier(0);
        __builtin_amdgcn_s_setprio(1);
        #pragma unroll
        for (int q = 0; q < 4; ++q)
            #pragma unroll
            for (int p = 0; p < NS; ++p)
                acc[q][p] = __builtin_amdgcn_mfma_f32_16x16x32_f16(af[q], bf[0][p], acc[q][p], 0, 0, 0);
        __builtin_amdgcn_s_setprio(0);

        // P2: A q0..3 kth1
        #pragma unroll
        for (int q = 0; q < 4; ++q) af[q] = pA[(16 + wm * 8 + q) * 64 + lane];
        asm volatile("s_waitcnt lgkmcnt(0)" ::: "memory");
        __builtin_amdgcn_sched_barrier(0);
        __builtin_amdgcn_s_setprio(1);
        #pragma unroll
        for (int q = 0; q < 4; ++q)
            #pragma unroll
            for (int p = 0; p < NS; ++p)
                acc[q][p] = __builtin_amdgcn_mfma_f32_16x16x32_f16(af[q], bf[1][p], acc[q][p], 0, 0, 0);
        __builtin_amdgcn_s_setprio(0);

        // P3: A q4..7 kth0
        #pragma unroll
        for (int q = 0; q < 4; ++q) af[q] = pA[(wm * 8 + 4 + q) * 64 + lane];
        asm volatile("s_waitcnt lgkmcnt(0)" ::: "memory");
        __builtin_amdgcn_sched_barrier(0);
        __builtin_amdgcn_s_setprio(1);
        #pragma unroll
        for (int q = 0; q < 4; ++q)
            #pragma unroll
            for (int p = 0; p < NS; ++p)
                acc[4 + q][p] = __builtin_amdgcn_mfma_f32_16x16x32_f16(af[q], bf[0][p], acc[4 + q][p], 0, 0, 0);
        __builtin_amdgcn_s_setprio(0);

        // P4: A q4..7 kth1, then barrier + prefetch kt+2 into buf[cur]
        #pragma unroll
        for (int q = 0; q < 4; ++q) af[q] = pA[(16 + wm * 8 + 4 + q) * 64 + lane];
        asm volatile("s_waitcnt lgkmcnt(0)" ::: "memory");
        __builtin_amdgcn_sched_barrier(0);
        __builtin_amdgcn_s_barrier();          // all waves done reading buf[cur]
        __builtin_amdgcn_sched_barrier(0);
        if (kt + 2 < NT) STAGE(cur, kt + 2);
        __builtin_amdgcn_sched_barrier(0);
        __builtin_amdgcn_s_setprio(1);
        #pragma unroll
        for (int q = 0; q < 4; ++q)
            #pragma unroll
            for (int p = 0; p < NS; ++p)
                acc[4 + q][p] = __builtin_amdgcn_mfma_f32_16x16x32_f16(af[q], bf[1][p], acc[4 + q][p], 0, 0, 0);
        __builtin_amdgcn_s_setprio(0);

        cur ^= 1;
    }
#undef STAGE

    // Epilogue. D frag: col = lane&15, row = (lane>>4)*4 + r.
    const int m0 = m_t * 256;
    const int n0 = n_t * NS * 64;
    #pragma unroll
    for (int q = 0; q < 8; ++q) {
        const int rbase = m0 + (wm * 8 + q) * 16 + (lane >> 4) * 4;
        #pragma unroll
        for (int p = 0; p < NS; ++p) {
            const int col = n0 + (wn * NS + p) * 16 + (lane & 15);
            const float bv = bias[col];
            #pragma unroll
            for (int r = 0; r < 4; ++r) {
                const int row = rbase + r;
                float v = acc[q][p][r] + bv;
                if (RESID) v = elu1(v) + R32[(size_t)row * DDIM + col];
                if (OUT32) C32[(size_t)row * N + col] = v;
                if (H16) {
                    const size_t hoff =
                        ((size_t)(col >> 5) * nms + (row >> 4)) * 1024
                        + (size_t)((row & 15) + (((col >> 3) & 3) << 4)) * 16
                        + (col & 7) * 2;
                    *(_Float16*)((char*)C16 + hoff) = (_Float16)v;
                }
            }
        }
    }
}

extern "C" void kernel_launch(void* const* d_in, const int* in_sizes, int n_in,
                              void* d_out, int out_size, void* d_ws, size_t ws_size,
                              hipStream_t stream) {
    const float* X          = (const float*)d_in[0];
    const int*   edge_index = (const int*)d_in[1];
    const int*   batch_vec  = (const int*)d_in[2];
    const int*   ptrv       = (const int*)d_in[3];
    const int*   sl         = (const int*)d_in[4];
    const int*   sr         = (const int*)d_in[5];
    const float* elem       = (const float*)d_in[6];
    const float* emb        = (const float*)d_in[7];
    const float* stat       = (const float*)d_in[8];
    const float* Wd         = (const float*)d_in[9];
    const float* bd         = (const float*)d_in[10];
    const float* Wo         = (const float*)d_in[11];
    const float* bo         = (const float*)d_in[12];
    float* out = (float*)d_out;

    _Float16* W16d = (_Float16*)d_ws;
    _Float16* W16o = W16d + (size_t)3 * DDIM * DDIM;
    int* perm = (int*)(W16o + (size_t)DDIM * OUTD);
    int* cnt  = perm + (size_t)MAXCHUNK * 64 * GCAP;
    char* hbase = (char*)(cnt + 64 * MAXCHUNK);
    hbase = (char*)(((size_t)hbase + 255) & ~(size_t)255);
    const size_t rem = ws_size - (size_t)(hbase - (char*)d_ws);

    int CH = EE;
    while (CH > 8192 && (size_t)CH * DDIM * 12 > rem) CH >>= 1;   // 12 B/elem
    const int nms = CH / 16;
    float* f32a = (float*)hbase;
    float* f32b = f32a + (size_t)CH * DDIM;
    _Float16* f16a = (_Float16*)(f32b + (size_t)CH * DDIM);
    _Float16* f16b = f16a + (size_t)CH * DDIM;

    prep_kernel<<<2721, 256, 0, stream>>>(Wd, Wo, W16d, W16o, cnt);

    int ci = 0;
    for (int e0 = 0; e0 < EE; e0 += CH, ++ci) {
        int* permc = perm + (size_t)ci * 64 * GCAP;
        int* cntc  = cnt + ci * 64;

        scatter_kernel<<<CH / 256, 256, 0, stream>>>(
            edge_index + e0, batch_vec, permc, cntc, CH);

        feats4_kernel<<<64 * (GCAP / 4), 256, 0, stream>>>(
            X, permc, cntc, edge_index + e0, edge_index + EE + e0, ptrv,
            sl + (size_t)e0 * KK, sr + (size_t)e0 * KK,
            elem + (size_t)e0 * 24, emb + (size_t)e0 * 200,
            stat + (size_t)e0 * 32, f32a, f16a, nms);

        const int gsq = (CH / 256) * 4;   // BM=256, BN=320
        mfma_gemm5<5, true, true, true><<<gsq, 512, 0, stream>>>(
            f16a, f32a, W16d + 0 * (size_t)DDIM * DDIM, bd + 0 * DDIM,
            f32b, f16b, DDIM, 80, nms);
        mfma_gemm5<5, true, true, true><<<gsq, 512, 0, stream>>>(
            f16b, f32b, W16d + 1 * (size_t)DDIM * DDIM, bd + 1 * DDIM,
            f32a, f16a, DDIM, 80, nms);
        mfma_gemm5<5, true, false, true><<<gsq, 512, 0, stream>>>(
            f16a, f32a, W16d + 2 * (size_t)DDIM * DDIM, bd + 2 * DDIM,
            nullptr, f16b, DDIM, 80, nms);

        const int gout = (CH / 256) * 2;  // BM=256, BN=256
        mfma_gemm5<4, false, true, false><<<gout, 512, 0, stream>>>(
            f16b, nullptr, W16o, bo, out + (size_t)e0 * OUTD, nullptr, OUTD, 32, nms);
    }
}

// Round 12
// 1000.101 us; speedup vs baseline: 1.1203x; 1.1203x over previous
//
#include <hip/hip_runtime.h>
#include <math.h>

#define NN   65536
#define EE   32768
#define HH   256
#define KK   24
#define DDIM 1280
#define OUTD 512
#define KT   (DDIM / 32)   // 40 K-steps of 32
#define GCAP 512
#define MAXCHUNK 4

typedef _Float16 half8 __attribute__((ext_vector_type(8)));
typedef _Float16 half4 __attribute__((ext_vector_type(4)));
typedef float    f32x4 __attribute__((ext_vector_type(4)));

__device__ __forceinline__ float elu1(float x) { return x > 0.f ? x : expm1f(x); }

// async global->LDS, 16B per lane; LDS dest is wave-uniform base + lane*16
__device__ __forceinline__ void gl16(const void* g, void* l) {
    __builtin_amdgcn_global_load_lds(
        (const __attribute__((address_space(1))) void*)g,
        (__attribute__((address_space(3))) void*)l, 16, 0, 0);
}

// ---------------------------------------------------------------------------
// prep: convert all 4 weight matrices fp32 -> fp16 fragment-major (m128-major
// tile contract, R7-era: tile of 128 cols x 32 k = 8 KB = 8 subtiles x 64
// chunks x 16 B), zero cnt.
// ---------------------------------------------------------------------------
__global__ __launch_bounds__(256) void prep_kernel(
    const float* __restrict__ Wd, const float* __restrict__ Wo,
    _Float16* __restrict__ W16d, _Float16* __restrict__ W16o,
    int* __restrict__ cnt)
{
    const int b = blockIdx.x;
    const int lane = threadIdx.x & 63;
    if (b < 2400) {                      // 3 square layers: 800 blocks each
        const int l = b / 800;
        const int s = (b % 800) * 4 + (threadIdx.x >> 6);
        const int nt = s & 7, nb = (s >> 3) % 10, kt = s / 80;
        const int kbase = kt * 32 + 8 * (lane >> 4);
        const int n     = nb * 128 + nt * 16 + (lane & 15);
        const float* W = Wd + (size_t)l * DDIM * DDIM;
        half8 v;
        #pragma unroll
        for (int j = 0; j < 8; ++j) v[j] = (_Float16)W[(size_t)(kbase + j) * DDIM + n];
        ((half8*)(W16d + (size_t)l * DDIM * DDIM))[(size_t)s * 64 + lane] = v;
    } else if (b < 2720) {               // output layer: 320 blocks
        const int s = (b - 2400) * 4 + (threadIdx.x >> 6);
        const int nt = s & 7, nb = (s >> 3) % 4, kt = s / 32;
        const int kbase = kt * 32 + 8 * (lane >> 4);
        const int n     = nb * 128 + nt * 16 + (lane & 15);
        half8 v;
        #pragma unroll
        for (int j = 0; j < 8; ++j) v[j] = (_Float16)Wo[(size_t)(kbase + j) * OUTD + n];
        ((half8*)W16o)[(size_t)s * 64 + lane] = v;
    } else {
        if (threadIdx.x < 64 * MAXCHUNK) cnt[threadIdx.x] = 0;
    }
}

// ---------------------------------------------------------------------------
// bucket edges by graph, LDS-aggregated (order-independent output)
// ---------------------------------------------------------------------------
__global__ __launch_bounds__(256) void scatter_kernel(
    const int* __restrict__ src_idx, const int* __restrict__ batch_vec,
    int* __restrict__ perm, int* __restrict__ cnt, int nE)
{
    __shared__ int lc[64];
    __shared__ int lbase[64];
    const int tid = threadIdx.x;
    if (tid < 64) lc[tid] = 0;
    __syncthreads();
    const int e = blockIdx.x * 256 + tid;
    int g = -1, li = 0;
    if (e < nE) {
        g = batch_vec[src_idx[e]];
        li = atomicAdd(&lc[g], 1);
    }
    __syncthreads();
    if (tid < 64 && lc[tid] > 0) lbase[tid] = atomicAdd(&cnt[tid], lc[tid]);
    __syncthreads();
    if (e >= nE) return;
    const int idx = lbase[g] + li;
    if (idx < GCAP) perm[g * GCAP + idx] = e;
}

// ---------------------------------------------------------------------------
// Feature assembly (graph-bucketed for XCD-L2 locality) writing BOTH
// row-major fp32 (residual stream) and fragment-major fp16 (GEMM A stream).
// ---------------------------------------------------------------------------
__global__ __launch_bounds__(256) void feats4_kernel(
    const float* __restrict__ X, const int* __restrict__ perm,
    const int* __restrict__ cnt,
    const int* __restrict__ src_idx, const int* __restrict__ dst_idx,
    const int* __restrict__ ptrv,
    const int* __restrict__ sl, const int* __restrict__ sr,
    const float* __restrict__ elem, const float* __restrict__ emb,
    const float* __restrict__ stat,
    float* __restrict__ F32, _Float16* __restrict__ F16)
{
    const int b  = blockIdx.x;
    const int x  = b & 7;
    const int j  = b >> 3;
    const int g  = x + 8 * (j >> 7);           // GCAP=512 -> 128 blocks/graph
    const int jj = j & 127;
    const int slot = jj * 4 + (threadIdx.x >> 6);
    const int ng = min(cnt[g], GCAP);
    if (slot >= ng) return;
    const int e = perm[g * GCAP + slot];

    const int lane = threadIdx.x & 63;
    const int src  = src_idx[e];
    const int dst  = dst_idx[e];
    const int off  = ptrv[g];

    const float4* X4 = (const float4*)X;
    float4* f4 = (float4*)(F32 + (size_t)e * DDIM);

    const size_t hb = ((size_t)(e >> 7) * 40) * 4096
                    + (size_t)((e & 127) >> 4) * 512
                    + (size_t)((e & 15) + (((lane >> 1) & 3) << 4)) * 8 + (lane & 1) * 4;
    const size_t hkt = (size_t)(lane >> 3) * 4096;
#define ST(seg, v)                                                            \
    {                                                                         \
        f4[(seg) * 64 + lane] = (v);                                          \
        half4 h_;                                                             \
        h_[0] = (_Float16)(v).x; h_[1] = (_Float16)(v).y;                     \
        h_[2] = (_Float16)(v).z; h_[3] = (_Float16)(v).w;                     \
        *(half4*)(F16 + hb + ((size_t)(seg) * 8) * 4096 + hkt) = h_;          \
    }

    ST(0, X4[(size_t)src * 64 + lane]);
    ST(1, X4[(size_t)dst * 64 + lane]);

    float4 sL = make_float4(0.f, 0.f, 0.f, 0.f);
    float4 sR = make_float4(0.f, 0.f, 0.f, 0.f);
    int cL = 0, cR = 0;
    #pragma unroll
    for (int k = 0; k < KK; ++k) {
        const int il  = sl[e * KK + k] + off;
        const int ir  = sr[e * KK + k] + off;
        const int okL = il >= 0;
        const int okR = ir >= 0;
        const float wL = okL ? 1.f : 0.f;
        const float wR = okR ? 1.f : 0.f;
        const float4 vl = X4[(size_t)(okL ? il : 0) * 64 + lane];
        const float4 vr = X4[(size_t)(okR ? ir : 0) * 64 + lane];
        sL.x += vl.x * wL; sL.y += vl.y * wL; sL.z += vl.z * wL; sL.w += vl.w * wL;
        sR.x += vr.x * wR; sR.y += vr.y * wR; sR.z += vr.z * wR; sR.w += vr.w * wR;
        cL += okL; cR += okR;
    }
    const float rL = cL > 0 ? 1.f / (float)cL : 0.f;
    const float rR = cR > 0 ? 1.f / (float)cR : 0.f;
    ST(2, make_float4(sL.x * rL, sL.y * rL, sL.z * rL, sL.w * rL));
    ST(3, make_float4(sR.x * rR, sR.y * rR, sR.z * rR, sR.w * rR));

    float4 tail;
    if (lane < 6)       tail = ((const float4*)(elem + (size_t)e * 24))[lane];
    else if (lane < 56) tail = ((const float4*)(emb  + (size_t)e * 200))[lane - 6];
    else                tail = ((const float4*)(stat + (size_t)e * 32))[lane - 56];
    ST(4, tail);
#undef ST
}

// ---------------------------------------------------------------------------
// MFMA GEMM (R9's proven gemm4): counted-vmcnt triple-buffer pipeline.
// ---------------------------------------------------------------------------
template<bool RESID, bool OUT32, bool H16>
__global__ __launch_bounds__(256) void mfma_gemm4(
    const _Float16* __restrict__ A16, const float* __restrict__ R32,
    const _Float16* __restrict__ W16, const float* __restrict__ bias,
    float* __restrict__ C32, _Float16* __restrict__ C16,
    int N, int nbN)
{
    __shared__ __align__(16) char sA[3][8192];
    __shared__ __align__(16) char sB[3][8192];

    const int t    = threadIdx.x;
    const int wid  = t >> 6;
    const int lane = t & 63;

    int m_t, n_t;
    if ((gridDim.y & 7) == 0) {
        const int flat = blockIdx.y * gridDim.x + blockIdx.x;
        m_t = (flat & 7) + 8 * (flat / (8 * gridDim.x));
        n_t = (flat >> 3) % gridDim.x;
    } else {
        m_t = blockIdx.y; n_t = blockIdx.x;
    }

    f32x4 acc[2][8];
    #pragma unroll
    for (int i = 0; i < 2; ++i)
        #pragma unroll
        for (int j = 0; j < 8; ++j) acc[i][j] = (f32x4){0.f, 0.f, 0.f, 0.f};

    const char* Abase = (const char*)A16 + (size_t)m_t * KT * 8192;
    const char* Bbase = (const char*)W16;

#define STAGE(d, ktv)                                                           \
    {                                                                           \
        const char* Ak = Abase + (size_t)(ktv) * 8192 + wid * 1024 + lane * 16; \
        const char* Bk = Bbase + ((size_t)(ktv) * nbN + n_t) * 8192             \
                         + wid * 1024 + lane * 16;                              \
        gl16(Ak,        sA[d] + wid * 1024);                                    \
        gl16(Ak + 4096, sA[d] + (4 + wid) * 1024);                              \
        gl16(Bk,        sB[d] + wid * 1024);                                    \
        gl16(Bk + 4096, sB[d] + (4 + wid) * 1024);                              \
    }

    STAGE(0, 0);
    STAGE(1, 1);
    STAGE(2, 2);

    int cur = 0;
    for (int kt = 0; kt < KT; ++kt) {
        if (kt + 2 < KT)      asm volatile("s_waitcnt vmcnt(8)" ::: "memory");
        else if (kt + 1 < KT) asm volatile("s_waitcnt vmcnt(4)" ::: "memory");
        else                  asm volatile("s_waitcnt vmcnt(0)" ::: "memory");
        __builtin_amdgcn_sched_barrier(0);
        __builtin_amdgcn_s_barrier();          // stage kt visible to all waves
        __builtin_amdgcn_sched_barrier(0);

        const half8* pa = (const half8*)sA[cur];
        const half8* pb = (const half8*)sB[cur];
        const half8 af0 = pa[(2 * wid)     * 64 + lane];
        const half8 af1 = pa[(2 * wid + 1) * 64 + lane];
        half8 bf[8];
        #pragma unroll
        for (int j = 0; j < 8; ++j) bf[j] = pb[j * 64 + lane];

        asm volatile("s_waitcnt lgkmcnt(0)" ::: "memory");
        __builtin_amdgcn_sched_barrier(0);
        __builtin_amdgcn_s_barrier();          // all waves done reading buf[cur]
        __builtin_amdgcn_sched_barrier(0);

        if (kt + 3 < KT) STAGE(cur, kt + 3);
        __builtin_amdgcn_sched_barrier(0);

        __builtin_amdgcn_s_setprio(1);
        #pragma unroll
        for (int j = 0; j < 8; ++j) {
            acc[0][j] = __builtin_amdgcn_mfma_f32_16x16x32_f16(af0, bf[j], acc[0][j], 0, 0, 0);
            acc[1][j] = __builtin_amdgcn_mfma_f32_16x16x32_f16(af1, bf[j], acc[1][j], 0, 0, 0);
        }
        __builtin_amdgcn_s_setprio(0);

        cur = (cur == 2) ? 0 : cur + 1;
    }
#undef STAGE

    // Epilogue. D layout: col = lane&15, row = (lane>>4)*4 + r.
    const int m0 = m_t * 128;
    #pragma unroll
    for (int i = 0; i < 2; ++i) {
        const int rbase = m0 + wid * 32 + i * 16 + (lane >> 4) * 4;
        #pragma unroll
        for (int j = 0; j < 8; ++j) {
            const int col = n_t * 128 + j * 16 + (lane & 15);
            const float bv = bias[col];
            #pragma unroll
            for (int r = 0; r < 4; ++r) {
                const int row = rbase + r;
                float v = acc[i][j][r] + bv;
                if (RESID) v = elu1(v) + R32[(size_t)row * DDIM + col];
                if (OUT32) C32[(size_t)row * N + col] = v;
                if (H16) {
                    const size_t hoff =
                        ((size_t)(row >> 7) * 40 + (size_t)(n_t * 4 + (j >> 1))) * 4096
                        + (size_t)((row >> 4) & 7) * 512
                        + (size_t)((row & 15) + (((j & 1) * 2 + ((lane >> 3) & 1)) << 4)) * 8
                        + (lane & 7);
                    C16[hoff] = (_Float16)v;
                }
            }
        }
    }
}

extern "C" void kernel_launch(void* const* d_in, const int* in_sizes, int n_in,
                              void* d_out, int out_size, void* d_ws, size_t ws_size,
                              hipStream_t stream) {
    const float* X          = (const float*)d_in[0];
    const int*   edge_index = (const int*)d_in[1];
    const int*   batch_vec  = (const int*)d_in[2];
    const int*   ptrv       = (const int*)d_in[3];
    const int*   sl         = (const int*)d_in[4];
    const int*   sr         = (const int*)d_in[5];
    const float* elem       = (const float*)d_in[6];
    const float* emb        = (const float*)d_in[7];
    const float* stat       = (const float*)d_in[8];
    const float* Wd         = (const float*)d_in[9];
    const float* bd         = (const float*)d_in[10];
    const float* Wo         = (const float*)d_in[11];
    const float* bo         = (const float*)d_in[12];
    float* out = (float*)d_out;

    // ws: [W16d x3 | W16o | perm | cnt | h32 a,b | h16 a,b]
    _Float16* W16d = (_Float16*)d_ws;
    _Float16* W16o = W16d + (size_t)3 * DDIM * DDIM;
    int* perm = (int*)(W16o + (size_t)DDIM * OUTD);
    int* cnt  = perm + (size_t)MAXCHUNK * 64 * GCAP;
    char* hbase = (char*)(cnt + 64 * MAXCHUNK);
    hbase = (char*)(((size_t)hbase + 255) & ~(size_t)255);
    const size_t rem = ws_size - (size_t)(hbase - (char*)d_ws);

    // L3-chunking: CH=8192 keeps the per-layer stream working set (~130 MB)
    // resident in the 256 MB Infinity Cache between consecutive GEMMs.
    int CH = 8192;
    while (CH > 2048 && (size_t)CH * DDIM * 12 > rem) CH >>= 1;   // 12 B/elem
    float* f32a = (float*)hbase;
    float* f32b = f32a + (size_t)CH * DDIM;
    _Float16* f16a = (_Float16*)(f32b + (size_t)CH * DDIM);
    _Float16* f16b = f16a + (size_t)CH * DDIM;

    prep_kernel<<<2721, 256, 0, stream>>>(Wd, Wo, W16d, W16o, cnt);

    int ci = 0;
    for (int e0 = 0; e0 < EE; e0 += CH, ++ci) {
        int* permc = perm + (size_t)(ci & (MAXCHUNK - 1)) * 64 * GCAP;
        int* cntc  = cnt + (ci & (MAXCHUNK - 1)) * 64;

        scatter_kernel<<<CH / 256, 256, 0, stream>>>(
            edge_index + e0, batch_vec, permc, cntc, CH);

        feats4_kernel<<<64 * (GCAP / 4), 256, 0, stream>>>(
            X, permc, cntc, edge_index + e0, edge_index + EE + e0, ptrv,
            sl + (size_t)e0 * KK, sr + (size_t)e0 * KK,
            elem + (size_t)e0 * 24, emb + (size_t)e0 * 200,
            stat + (size_t)e0 * 32, f32a, f16a);

        dim3 gd(10, CH / 128);
        mfma_gemm4<true, true, true><<<gd, 256, 0, stream>>>(
            f16a, f32a, W16d + 0 * (size_t)DDIM * DDIM, bd + 0 * DDIM,
            f32b, f16b, DDIM, 10);
        mfma_gemm4<true, true, true><<<gd, 256, 0, stream>>>(
            f16b, f32b, W16d + 1 * (size_t)DDIM * DDIM, bd + 1 * DDIM,
            f32a, f16a, DDIM, 10);
        mfma_gemm4<true, false, true><<<gd, 256, 0, stream>>>(
            f16a, f32a, W16d + 2 * (size_t)DDIM * DDIM, bd + 2 * DDIM,
            nullptr, f16b, DDIM, 10);

        dim3 go(4, CH / 128);
        mfma_gemm4<false, true, false><<<go, 256, 0, stream>>>(
            f16b, nullptr, W16o, bo, out + (size_t)e0 * OUTD, nullptr, OUTD, 4);
    }
}

// Round 14
// 930.860 us; speedup vs baseline: 1.2036x; 1.0744x over previous
//
#include <hip/hip_runtime.h>
#include <math.h>

#define NN   65536
#define EE   32768
#define HH   256
#define KK   24
#define DDIM 1280
#define OUTD 512
#define KT   (DDIM / 32)   // 40 K-steps of 32
#define GCAP 512
#define MAXCHUNK 4

typedef _Float16 half8 __attribute__((ext_vector_type(8)));
typedef _Float16 half4 __attribute__((ext_vector_type(4)));
typedef float    f32x4 __attribute__((ext_vector_type(4)));

__device__ __forceinline__ float elu1(float x) { return x > 0.f ? x : expm1f(x); }

// async global->LDS, 16B per lane; LDS dest is wave-uniform base + lane*16
__device__ __forceinline__ void gl16(const void* g, void* l) {
    __builtin_amdgcn_global_load_lds(
        (const __attribute__((address_space(1))) void*)g,
        (__attribute__((address_space(3))) void*)l, 16, 0, 0);
}

// ---------------------------------------------------------------------------
// Fragment-major layout (all h streams + weights): element (row, k) ->
// idx = ((row>>7)*KT + (k>>5))*4096 + ((row>>4)&7)*512
//       + ((row&15) + 16*((k&31)>>3))*8 + (k&7)
// i.e. per 128-row x 32-k tile: 8 subtiles x 64 chunks x 8 halves.
// ---------------------------------------------------------------------------
__global__ __launch_bounds__(256) void prep_kernel(
    const float* __restrict__ Wd, const float* __restrict__ Wo,
    _Float16* __restrict__ W16d, _Float16* __restrict__ W16o,
    int* __restrict__ cnt)
{
    const int b = blockIdx.x;
    const int lane = threadIdx.x & 63;
    if (b < 2400) {                      // 3 square layers: 800 blocks each
        const int l = b / 800;
        const int s = (b % 800) * 4 + (threadIdx.x >> 6);
        const int nt = s & 7, nb = (s >> 3) % 10, kt = s / 80;
        const int kbase = kt * 32 + 8 * (lane >> 4);
        const int n     = nb * 128 + nt * 16 + (lane & 15);
        const float* W = Wd + (size_t)l * DDIM * DDIM;
        half8 v;
        #pragma unroll
        for (int j = 0; j < 8; ++j) v[j] = (_Float16)W[(size_t)(kbase + j) * DDIM + n];
        ((half8*)(W16d + (size_t)l * DDIM * DDIM))[(size_t)s * 64 + lane] = v;
    } else if (b < 2720) {               // output layer: 320 blocks
        const int s = (b - 2400) * 4 + (threadIdx.x >> 6);
        const int nt = s & 7, nb = (s >> 3) % 4, kt = s / 32;
        const int kbase = kt * 32 + 8 * (lane >> 4);
        const int n     = nb * 128 + nt * 16 + (lane & 15);
        half8 v;
        #pragma unroll
        for (int j = 0; j < 8; ++j) v[j] = (_Float16)Wo[(size_t)(kbase + j) * OUTD + n];
        ((half8*)W16o)[(size_t)s * 64 + lane] = v;
    } else {
        if (threadIdx.x < 64 * MAXCHUNK) cnt[threadIdx.x] = 0;
    }
}

// ---------------------------------------------------------------------------
// bucket edges by graph, LDS-aggregated (order-independent output)
// ---------------------------------------------------------------------------
__global__ __launch_bounds__(256) void scatter_kernel(
    const int* __restrict__ src_idx, const int* __restrict__ batch_vec,
    int* __restrict__ perm, int* __restrict__ cnt, int nE)
{
    __shared__ int lc[64];
    __shared__ int lbase[64];
    const int tid = threadIdx.x;
    if (tid < 64) lc[tid] = 0;
    __syncthreads();
    const int e = blockIdx.x * 256 + tid;
    int g = -1, li = 0;
    if (e < nE) {
        g = batch_vec[src_idx[e]];
        li = atomicAdd(&lc[g], 1);
    }
    __syncthreads();
    if (tid < 64 && lc[tid] > 0) lbase[tid] = atomicAdd(&cnt[tid], lc[tid]);
    __syncthreads();
    if (e >= nE) return;
    const int idx = lbase[g] + li;
    if (idx < GCAP) perm[g * GCAP + idx] = e;
}

// ---------------------------------------------------------------------------
// Feature assembly (graph-bucketed for XCD-L2 locality), fp16 fragment-major
// output ONLY (the fp32 stream is gone; residual is re-read from F16).
// ---------------------------------------------------------------------------
__global__ __launch_bounds__(256) void feats16_kernel(
    const float* __restrict__ X, const int* __restrict__ perm,
    const int* __restrict__ cnt,
    const int* __restrict__ src_idx, const int* __restrict__ dst_idx,
    const int* __restrict__ ptrv,
    const int* __restrict__ sl, const int* __restrict__ sr,
    const float* __restrict__ elem, const float* __restrict__ emb,
    const float* __restrict__ stat,
    _Float16* __restrict__ F16)
{
    const int b  = blockIdx.x;
    const int x  = b & 7;
    const int j  = b >> 3;
    const int g  = x + 8 * (j >> 7);           // GCAP=512 -> 128 blocks/graph
    const int jj = j & 127;
    const int slot = jj * 4 + (threadIdx.x >> 6);
    const int ng = min(cnt[g], GCAP);
    if (slot >= ng) return;
    const int e = perm[g * GCAP + slot];

    const int lane = threadIdx.x & 63;
    const int src  = src_idx[e];
    const int dst  = dst_idx[e];
    const int off  = ptrv[g];

    const float4* X4 = (const float4*)X;

    // fragment-major half4 dest: kt32 = seg*8 + lane/8,
    // chunk = (e%16) + 16*((lane%8)/2), element (lane&1)*4.
    const size_t hb = ((size_t)(e >> 7) * 40) * 4096
                    + (size_t)((e & 127) >> 4) * 512
                    + (size_t)((e & 15) + (((lane >> 1) & 3) << 4)) * 8 + (lane & 1) * 4;
    const size_t hkt = (size_t)(lane >> 3) * 4096;
#define ST(seg, v)                                                            \
    {                                                                         \
        half4 h_;                                                             \
        h_[0] = (_Float16)(v).x; h_[1] = (_Float16)(v).y;                     \
        h_[2] = (_Float16)(v).z; h_[3] = (_Float16)(v).w;                     \
        *(half4*)(F16 + hb + ((size_t)(seg) * 8) * 4096 + hkt) = h_;          \
    }

    ST(0, X4[(size_t)src * 64 + lane]);
    ST(1, X4[(size_t)dst * 64 + lane]);

    float4 sL = make_float4(0.f, 0.f, 0.f, 0.f);
    float4 sR = make_float4(0.f, 0.f, 0.f, 0.f);
    int cL = 0, cR = 0;
    #pragma unroll
    for (int k = 0; k < KK; ++k) {
        const int il  = sl[e * KK + k] + off;
        const int ir  = sr[e * KK + k] + off;
        const int okL = il >= 0;
        const int okR = ir >= 0;
        const float wL = okL ? 1.f : 0.f;
        const float wR = okR ? 1.f : 0.f;
        const float4 vl = X4[(size_t)(okL ? il : 0) * 64 + lane];
        const float4 vr = X4[(size_t)(okR ? ir : 0) * 64 + lane];
        sL.x += vl.x * wL; sL.y += vl.y * wL; sL.z += vl.z * wL; sL.w += vl.w * wL;
        sR.x += vr.x * wR; sR.y += vr.y * wR; sR.z += vr.z * wR; sR.w += vr.w * wR;
        cL += okL; cR += okR;
    }
    const float rL = cL > 0 ? 1.f / (float)cL : 0.f;
    const float rR = cR > 0 ? 1.f / (float)cR : 0.f;
    ST(2, make_float4(sL.x * rL, sL.y * rL, sL.z * rL, sL.w * rL));
    ST(3, make_float4(sR.x * rR, sR.y * rR, sR.z * rR, sR.w * rR));

    float4 tail;
    if (lane < 6)       tail = ((const float4*)(elem + (size_t)e * 24))[lane];
    else if (lane < 56) tail = ((const float4*)(emb  + (size_t)e * 200))[lane - 6];
    else                tail = ((const float4*)(stat + (size_t)e * 32))[lane - 56];
    ST(4, tail);
#undef ST
}

// ---------------------------------------------------------------------------
// MFMA GEMM, counted-vmcnt triple-buffer pipeline (R9 structure). Residual
// is read from the A16 fragment-major buffer itself (same values, fp16) --
// the block's own A panel is L2-hot from staging, and the index formula is
// identical to the C16-write formula (same layout).
// ---------------------------------------------------------------------------
template<bool RESID, bool OUT32, bool H16>
__global__ __launch_bounds__(256) void mfma_gemm6(
    const _Float16* __restrict__ A16,
    const _Float16* __restrict__ W16, const float* __restrict__ bias,
    float* __restrict__ C32, _Float16* __restrict__ C16,
    int N, int nbN)
{
    __shared__ __align__(16) char sA[3][8192];
    __shared__ __align__(16) char sB[3][8192];

    const int t    = threadIdx.x;
    const int wid  = t >> 6;
    const int lane = t & 63;

    int m_t, n_t;
    if ((gridDim.y & 7) == 0) {     // XCD-affinity: all n-blocks of an m-tile
        const int flat = blockIdx.y * gridDim.x + blockIdx.x;
        m_t = (flat & 7) + 8 * (flat / (8 * gridDim.x));
        n_t = (flat >> 3) % gridDim.x;
    } else {
        m_t = blockIdx.y; n_t = blockIdx.x;
    }

    f32x4 acc[2][8];
    #pragma unroll
    for (int i = 0; i < 2; ++i)
        #pragma unroll
        for (int j = 0; j < 8; ++j) acc[i][j] = (f32x4){0.f, 0.f, 0.f, 0.f};

    const char* Abase = (const char*)A16 + (size_t)m_t * KT * 8192;
    const char* Bbase = (const char*)W16;

#define STAGE(d, ktv)                                                           \
    {                                                                           \
        const char* Ak = Abase + (size_t)(ktv) * 8192 + wid * 1024 + lane * 16; \
        const char* Bk = Bbase + ((size_t)(ktv) * nbN + n_t) * 8192             \
                         + wid * 1024 + lane * 16;                              \
        gl16(Ak,        sA[d] + wid * 1024);                                    \
        gl16(Ak + 4096, sA[d] + (4 + wid) * 1024);                              \
        gl16(Bk,        sB[d] + wid * 1024);                                    \
        gl16(Bk + 4096, sB[d] + (4 + wid) * 1024);                              \
    }

    STAGE(0, 0);
    STAGE(1, 1);
    STAGE(2, 2);

    int cur = 0;
    for (int kt = 0; kt < KT; ++kt) {
        if (kt + 2 < KT)      asm volatile("s_waitcnt vmcnt(8)" ::: "memory");
        else if (kt + 1 < KT) asm volatile("s_waitcnt vmcnt(4)" ::: "memory");
        else                  asm volatile("s_waitcnt vmcnt(0)" ::: "memory");
        __builtin_amdgcn_sched_barrier(0);
        __builtin_amdgcn_s_barrier();          // stage kt visible to all waves
        __builtin_amdgcn_sched_barrier(0);

        const half8* pa = (const half8*)sA[cur];
        const half8* pb = (const half8*)sB[cur];
        const half8 af0 = pa[(2 * wid)     * 64 + lane];
        const half8 af1 = pa[(2 * wid + 1) * 64 + lane];
        half8 bf[8];
        #pragma unroll
        for (int j = 0; j < 8; ++j) bf[j] = pb[j * 64 + lane];

        asm volatile("s_waitcnt lgkmcnt(0)" ::: "memory");
        __builtin_amdgcn_sched_barrier(0);
        __builtin_amdgcn_s_barrier();          // all waves done reading buf[cur]
        __builtin_amdgcn_sched_barrier(0);

        if (kt + 3 < KT) STAGE(cur, kt + 3);
        __builtin_amdgcn_sched_barrier(0);

        __builtin_amdgcn_s_setprio(1);
        #pragma unroll
        for (int j = 0; j < 8; ++j) {
            acc[0][j] = __builtin_amdgcn_mfma_f32_16x16x32_f16(af0, bf[j], acc[0][j], 0, 0, 0);
            acc[1][j] = __builtin_amdgcn_mfma_f32_16x16x32_f16(af1, bf[j], acc[1][j], 0, 0, 0);
        }
        __builtin_amdgcn_s_setprio(0);

        cur = (cur == 2) ? 0 : cur + 1;
    }
#undef STAGE

    // Epilogue. D frag: col = lane&15 within subtile, row = (lane>>4)*4 + r.
    // `off` is the fragment-major index of (row, col) -- used for BOTH the
    // residual read (A16) and the h16 write (C16), identical layout.
    const int m0 = m_t * 128;
    #pragma unroll
    for (int i = 0; i < 2; ++i) {
        #pragma unroll
        for (int j = 0; j < 8; ++j) {
            const int col = n_t * 128 + j * 16 + (lane & 15);
            const float bv = bias[col];
            const size_t tbase =
                ((size_t)m_t * 40 + (size_t)(n_t * 4 + (j >> 1))) * 4096
                + (size_t)(wid * 2 + i) * 512
                + (size_t)(((j & 1) * 2 + ((lane >> 3) & 1)) << 4) * 8
                + (lane & 7);
            #pragma unroll
            for (int r = 0; r < 4; ++r) {
                const int row = m0 + wid * 32 + i * 16 + (lane >> 4) * 4 + r;
                const size_t off = tbase + (size_t)((lane >> 4) * 4 + r) * 8;
                float v = acc[i][j][r] + bv;
                if (RESID) v = elu1(v) + (float)A16[off];
                if (OUT32) C32[(size_t)row * N + col] = v;
                if (H16)  C16[off] = (_Float16)v;
            }
        }
    }
}

extern "C" void kernel_launch(void* const* d_in, const int* in_sizes, int n_in,
                              void* d_out, int out_size, void* d_ws, size_t ws_size,
                              hipStream_t stream) {
    const float* X          = (const float*)d_in[0];
    const int*   edge_index = (const int*)d_in[1];
    const int*   batch_vec  = (const int*)d_in[2];
    const int*   ptrv       = (const int*)d_in[3];
    const int*   sl         = (const int*)d_in[4];
    const int*   sr         = (const int*)d_in[5];
    const float* elem       = (const float*)d_in[6];
    const float* emb        = (const float*)d_in[7];
    const float* stat       = (const float*)d_in[8];
    const float* Wd         = (const float*)d_in[9];
    const float* bd         = (const float*)d_in[10];
    const float* Wo         = (const float*)d_in[11];
    const float* bo         = (const float*)d_in[12];
    float* out = (float*)d_out;

    // ws: [W16d x3 | W16o | perm | cnt | h16 a,b]
    _Float16* W16d = (_Float16*)d_ws;
    _Float16* W16o = W16d + (size_t)3 * DDIM * DDIM;
    int* perm = (int*)(W16o + (size_t)DDIM * OUTD);
    int* cnt  = perm + (size_t)MAXCHUNK * 64 * GCAP;
    char* hbase = (char*)(cnt + 64 * MAXCHUNK);
    hbase = (char*)(((size_t)hbase + 255) & ~(size_t)255);
    const size_t rem = ws_size - (size_t)(hbase - (char*)d_ws);

    // fp16-only h streams: working set ~95 MB at CH=16384 -> L3-resident.
    int CH = 16384;
    while (CH > 2048 && (size_t)CH * DDIM * 4 > rem) CH >>= 1;   // 4 B/elem
    _Float16* f16a = (_Float16*)hbase;
    _Float16* f16b = f16a + (size_t)CH * DDIM;

    prep_kernel<<<2721, 256, 0, stream>>>(Wd, Wo, W16d, W16o, cnt);

    int ci = 0;
    for (int e0 = 0; e0 < EE; e0 += CH, ++ci) {
        int* permc = perm + (size_t)(ci & (MAXCHUNK - 1)) * 64 * GCAP;
        int* cntc  = cnt + (ci & (MAXCHUNK - 1)) * 64;

        scatter_kernel<<<CH / 256, 256, 0, stream>>>(
            edge_index + e0, batch_vec, permc, cntc, CH);

        feats16_kernel<<<64 * (GCAP / 4), 256, 0, stream>>>(
            X, permc, cntc, edge_index + e0, edge_index + EE + e0, ptrv,
            sl + (size_t)e0 * KK, sr + (size_t)e0 * KK,
            elem + (size_t)e0 * 24, emb + (size_t)e0 * 200,
            stat + (size_t)e0 * 32, f16a);

        dim3 gd(10, CH / 128);
        mfma_gemm6<true, false, true><<<gd, 256, 0, stream>>>(
            f16a, W16d + 0 * (size_t)DDIM * DDIM, bd + 0 * DDIM,
            nullptr, f16b, DDIM, 10);
        mfma_gemm6<true, false, true><<<gd, 256, 0, stream>>>(
            f16b, W16d + 1 * (size_t)DDIM * DDIM, bd + 1 * DDIM,
            nullptr, f16a, DDIM, 10);
        mfma_gemm6<true, false, true><<<gd, 256, 0, stream>>>(
            f16a, W16d + 2 * (size_t)DDIM * DDIM, bd + 2 * DDIM,
            nullptr, f16b, DDIM, 10);

        dim3 go(4, CH / 128);
        mfma_gemm6<false, true, false><<<go, 256, 0, stream>>>(
            f16b, W16o, bo, out + (size_t)e0 * OUTD, nullptr, OUTD, 4);
    }
}